// Round 7
// baseline (708.800 us; speedup 1.0000x reference)
//
#include <hip/hip_runtime.h>
#include <stdint.h>

#define NP 25088   // B * oH * oW = 8*56*56
#define DD 576     // 64 * 3 * 3
#define KC 256     // centroids

// ---------------- unfold: x[8,64,56,56] -> P^T[576][25088], d = c*9+i*3+j ----
__global__ __launch_bounds__(256) void unfold_kernel(const float* __restrict__ x,
                                                     float* __restrict__ PT) {
  const int d = blockIdx.y;                       // 0..575
  const int n = blockIdx.x * 256 + threadIdx.x;   // 0..25087
  const int c = d / 9, r = d % 9;
  const int di = r / 3 - 1, dj = r % 3 - 1;
  const int b = n / 3136, hw = n % 3136;
  const int h = hw / 56 + di, w = hw % 56 + dj;
  float v = 0.0f;
  if (h >= 0 && h < 56 && w >= 0 && w < 56)
    v = x[(((size_t)b * 64 + c) * 56 + h) * 56 + w];
  PT[(size_t)d * NP + n] = v;
}

// ---------------- centroid transpose: C[256][576] -> C^T[576][256] -----------
__global__ __launch_bounds__(256) void transpose_kernel(const float* __restrict__ C,
                                                        float* __restrict__ CT) {
  const int d = blockIdx.x;      // 576
  const int k = threadIdx.x;     // 256
  CT[d * KC + k] = C[k * DD + d];
}

// ---------------- nearest: per-block best over a 64-k slab -------------------
// R4 config (best: 287us): 64m x 64k block, 4m x 4k thread tile, Dc=32,
// 32 KB LDS -> 5 blocks/CU = 20 waves/CU, grid 1568 XCD-chunk swizzled.
// THIS ROUND: global_load_lds (width=16) staging replaces the
// global->VGPR->ds_write path: no per-chunk vmcnt(0)-before-write
// serialization, no ds_write instrs, fewer VALU/VGPRs. LDS dest is
// wave-uniform base + lane*16 (linear lane order by construction).
#define ACC4(p, a, s) \
  do { p.x += fabsf(a.x - (s)); p.y += fabsf(a.y - (s)); \
       p.z += fabsf(a.z - (s)); p.w += fabsf(a.w - (s)); } while (0)
#define ADD4(t, p) \
  do { t.x += p.x; t.y += p.y; t.z += p.z; t.w += p.w; } while (0)
#define COMP(v, i) ((i) == 0 ? (v).x : (i) == 1 ? (v).y : (i) == 2 ? (v).z : (v).w)

__device__ __forceinline__ void gl16(const float* g, float* l) {
  __builtin_amdgcn_global_load_lds(
      (const __attribute__((address_space(1))) void*)(uintptr_t)g,
      (__attribute__((address_space(3))) void*)(uintptr_t)l, 16, 0, 0);
}

__global__ __launch_bounds__(256, 5) void nearest_kernel(const float* __restrict__ AT,
                                                         const float* __restrict__ CT,
                                                         float* __restrict__ distc,
                                                         int* __restrict__ idxc) {
  __shared__ __align__(16) float As[2][32][64];    // [buf][d][m]   16 KB
  __shared__ __align__(16) float Bs[2][32][64];    // [buf][d][k]   16 KB

  const int tid = threadIdx.x;
  const int lane = tid & 63, wv = tid >> 6;
  const int tm = tid >> 4;           // 0..15 -> m = m0 + tm*4 + i
  const int tk = tid & 15;           // 0..15 -> k = k0 + tk*4 + j
  // XCD-chunk swizzle: XCD x gets m-groups [49x, 49x+49), 4 k-slabs adjacent.
  const int L = blockIdx.x;          // 0..1567 (= 8 * 196)
  const int xcd = L & 7, r = L >> 3;     // r 0..195
  const int mb = xcd * 49 + (r >> 2);    // 0..391
  const int kc = r & 3;                  // 0..3
  const int m0 = mb * 64, k0 = kc * 64;

  // DMA staging: wave wv fills rows [wv*8, wv*8+8) of each 32x64 tile.
  // Instr i covers rows wv*8+i*4 .. +4: lane L -> row +L/16, col (L%16)*4,
  // LDS flat offset = lane*16 bytes from the uniform base. All 16B-aligned.
  const int lr = lane >> 4, lc = (lane & 15) * 4;
  const float* apg = AT + (size_t)(wv * 8 + lr) * NP + m0 + lc;
  const float* bpg = CT + (size_t)(wv * 8 + lr) * KC + k0 + lc;

#define STAGE(bf) do {                                     \
    gl16(apg,              &As[bf][wv * 8][0]);            \
    gl16(apg + 4 * NP,     &As[bf][wv * 8 + 4][0]);        \
    gl16(bpg,              &Bs[bf][wv * 8][0]);            \
    gl16(bpg + 4 * KC,     &Bs[bf][wv * 8 + 4][0]);        \
    apg += (size_t)32 * NP; bpg += 32 * KC;                \
  } while (0)

  // accumulators: named float4 only (R4 lesson: array locals => scratch).
  float4 p0, p1, p2, p3, t0, t1, t2, t3;

  STAGE(0);
  t0 = t1 = t2 = t3 = make_float4(0.f, 0.f, 0.f, 0.f);
  __syncthreads();                             // drain prologue DMA

  for (int ch = 0; ch < 18; ++ch) {            // 18 * 32 = 576 d's
    if ((ch & 1) == 0) p0 = p1 = p2 = p3 = make_float4(0.f, 0.f, 0.f, 0.f);
    if (ch < 17) STAGE((ch + 1) & 1);          // issue next-chunk DMA first
    const float (*__restrict__ Asb)[64] = As[ch & 1];
    const float (*__restrict__ Bsb)[64] = Bs[ch & 1];
#pragma unroll 8
    for (int d = 0; d < 32; ++d) {
      const float4 a = *(const float4*)&Asb[d][tm * 4];
      const float4 b = *(const float4*)&Bsb[d][tk * 4];
      ACC4(p0, a, b.x);
      ACC4(p1, a, b.y);
      ACC4(p2, a, b.z);
      ACC4(p3, a, b.w);
    }
    if (ch & 1) {                              // segment flush (64 d's)
      ADD4(t0, p0); ADD4(t1, p1); ADD4(t2, p2); ADD4(t3, p3);
    }
    __syncthreads();                           // drains DMA (vmcnt) + guards buf reuse
  }

  // per-thread argmin over its 4 k's (ascending, strict < => first-min),
  // then butterfly reduce across the 16 tk lanes sharing this m-row.
#pragma unroll
  for (int i = 0; i < 4; ++i) {
    const float d0 = COMP(t0, i), d1 = COMP(t1, i), d2 = COMP(t2, i), d3 = COMP(t3, i);
    float bd = d0;
    int bk = k0 + tk * 4;
    if (d1 < bd) { bd = d1; bk = k0 + tk * 4 + 1; }
    if (d2 < bd) { bd = d2; bk = k0 + tk * 4 + 2; }
    if (d3 < bd) { bd = d3; bk = k0 + tk * 4 + 3; }
#pragma unroll
    for (int off = 1; off < 16; off <<= 1) {
      const float od = __shfl_xor(bd, off, 64);
      const int ok = __shfl_xor(bk, off, 64);
      if (od < bd || (od == bd && ok < bk)) { bd = od; bk = ok; }
    }
    if (tk == 0) {
      const int m = m0 + tm * 4 + i;
      distc[(size_t)kc * NP + m] = bd;
      idxc[(size_t)kc * NP + m] = bk;
    }
  }
#undef STAGE
}

// ---------------- combine the four k-slab candidates (tie -> lower k) --------
__global__ __launch_bounds__(256) void combine_kernel(const float* __restrict__ distc,
                                                      const int* __restrict__ idxc,
                                                      int* __restrict__ idx_out) {
  const int n = blockIdx.x * 256 + threadIdx.x;
  if (n >= NP) return;
  float bd = distc[n];
  int bi = idxc[n];
#pragma unroll
  for (int s = 1; s < 4; ++s) {
    const float d = distc[(size_t)s * NP + n];
    if (d < bd) { bd = d; bi = idxc[(size_t)s * NP + n]; }  // tie keeps lower slab
  }
  idx_out[n] = bi;
}

// ---------------- residual in place: P^T[d][n] -= C1^T[d][idx1[n]] -----------
__global__ __launch_bounds__(256) void resid_kernel(float* __restrict__ PT,
                                                    const float* __restrict__ C1T,
                                                    const int* __restrict__ idx1) {
  const int d = blockIdx.y;
  const int n = blockIdx.x * 256 + threadIdx.x;
  const int k = idx1[n];
  PT[(size_t)d * NP + n] -= C1T[d * KC + k];
}

// ---------------- BN stats: per-channel sum & sumsq of LUT outputs -----------
__global__ __launch_bounds__(256) void stats_kernel(const int* __restrict__ idx1,
                                                    const int* __restrict__ idx2,
                                                    const float* __restrict__ dotc,
                                                    const float* __restrict__ dotrc,
                                                    float* __restrict__ gsum,
                                                    float* __restrict__ gsq) {
  __shared__ float ssum[4][128], ssq[4][128];
  const int tid = threadIdx.x, lane = tid & 63, wv = tid >> 6;
  const int wid = blockIdx.x * 4 + wv;           // 0..511
  float s0 = 0.f, s1 = 0.f, q0 = 0.f, q1 = 0.f;
  for (int n = wid; n < NP; n += 512) {          // 25088 = 512*49
    const int k1 = idx1[n], k2 = idx2[n];
    const float2 u = ((const float2*)(dotc + (size_t)k1 * 128))[lane];
    const float2 v = ((const float2*)(dotrc + (size_t)k2 * 128))[lane];
    const float x0 = u.x + v.x, x1 = u.y + v.y;
    s0 += x0; s1 += x1; q0 += x0 * x0; q1 += x1 * x1;
  }
  ssum[wv][lane * 2] = s0; ssum[wv][lane * 2 + 1] = s1;
  ssq[wv][lane * 2] = q0;  ssq[wv][lane * 2 + 1] = q1;
  __syncthreads();
  if (tid < 128) {
    const float s = ssum[0][tid] + ssum[1][tid] + ssum[2][tid] + ssum[3][tid];
    const float q = ssq[0][tid] + ssq[1][tid] + ssq[2][tid] + ssq[3][tid];
    atomicAdd(&gsum[tid], s);
    atomicAdd(&gsq[tid], q);
  }
}

__global__ void finalize_kernel(const float* __restrict__ gsum,
                                const float* __restrict__ gsq,
                                const float* __restrict__ gamma,
                                const float* __restrict__ beta,
                                float* __restrict__ scalev,
                                float* __restrict__ shiftv) {
  const int c = threadIdx.x;                     // 128
  const float mean = gsum[c] * (1.0f / NP);
  const float var = gsq[c] * (1.0f / NP) - mean * mean;
  const float inv = rsqrtf(var + 1e-5f);
  const float sc = gamma[c] * inv;
  scalev[c] = sc;
  shiftv[c] = beta[c] - mean * sc;
}

// ---------------- output: LUT gather + affine BN + [B,C,H,W] store -----------
__global__ __launch_bounds__(256) void output_kernel(const int* __restrict__ idx1,
                                                     const int* __restrict__ idx2,
                                                     const float* __restrict__ dotc,
                                                     const float* __restrict__ dotrc,
                                                     const float* __restrict__ scalev,
                                                     const float* __restrict__ shiftv,
                                                     float* __restrict__ out) {
  __shared__ float vals[64][128];                // [n-local][c]  32 KB
  const int tid = threadIdx.x, lane = tid & 63, wv = tid >> 6;
  const int blk = blockIdx.x;                    // 392 = 8 * 49
  const int b = blk / 49, hw0 = (blk % 49) * 64;
  const int n0 = b * 3136 + hw0;
  const float sc0 = scalev[lane * 2], sc1 = scalev[lane * 2 + 1];
  const float sh0 = shiftv[lane * 2], sh1 = shiftv[lane * 2 + 1];
  for (int t = 0; t < 16; ++t) {
    const int nn = wv * 16 + t;
    const int n = n0 + nn;
    const int k1 = idx1[n], k2 = idx2[n];
    const float2 u = ((const float2*)(dotc + (size_t)k1 * 128))[lane];
    const float2 v = ((const float2*)(dotrc + (size_t)k2 * 128))[lane];
    *(float2*)&vals[nn][lane * 2] =
        make_float2(sc0 * (u.x + v.x) + sh0, sc1 * (u.y + v.y) + sh1);
  }
  __syncthreads();
  const int c = tid >> 1, half = tid & 1;
  float* op = out + ((size_t)b * 128 + c) * 3136 + hw0 + half * 32;
#pragma unroll
  for (int i = 0; i < 32; i += 4) {
    float4 w4;
    w4.x = vals[half * 32 + i + 0][c];
    w4.y = vals[half * 32 + i + 1][c];
    w4.z = vals[half * 32 + i + 2][c];
    w4.w = vals[half * 32 + i + 3][c];
    *(float4*)(op + i) = w4;
  }
}

extern "C" void kernel_launch(void* const* d_in, const int* in_sizes, int n_in,
                              void* d_out, int out_size, void* d_ws, size_t ws_size,
                              hipStream_t stream) {
  const float* x     = (const float*)d_in[0];
  const float* cent  = (const float*)d_in[1];
  const float* rcent = (const float*)d_in[2];
  const float* dotc  = (const float*)d_in[3];
  const float* dotrc = (const float*)d_in[4];
  const float* gamma = (const float*)d_in[5];
  const float* beta  = (const float*)d_in[6];
  float* out = (float*)d_out;

  // workspace layout (~60 MB)
  float* PT  = (float*)d_ws;                 // [576][25088]
  float* C1T = PT + (size_t)DD * NP;         // [576][256]
  float* C2T = C1T + (size_t)DD * KC;        // [576][256]
  int* idx1  = (int*)(C2T + (size_t)DD * KC);
  int* idx2  = idx1 + NP;
  float* distc = (float*)(idx2 + NP);        // [4][25088]
  int* idxc    = (int*)(distc + 4 * NP);     // [4][25088]
  float* gsum   = (float*)(idxc + 4 * NP);   // [128]
  float* gsq    = gsum + 128;                // [128]
  float* scalev = gsq + 128;                 // [128]
  float* shiftv = scalev + 128;              // [128]

  unfold_kernel<<<dim3(98, 576), 256, 0, stream>>>(x, PT);
  transpose_kernel<<<576, 256, 0, stream>>>(cent, C1T);
  transpose_kernel<<<576, 256, 0, stream>>>(rcent, C2T);
  nearest_kernel<<<1568, 256, 0, stream>>>(PT, C1T, distc, idxc);
  combine_kernel<<<98, 256, 0, stream>>>(distc, idxc, idx1);
  resid_kernel<<<dim3(98, 576), 256, 0, stream>>>(PT, C1T, idx1);
  nearest_kernel<<<1568, 256, 0, stream>>>(PT, C2T, distc, idxc);
  combine_kernel<<<98, 256, 0, stream>>>(distc, idxc, idx2);
  hipMemsetAsync(gsum, 0, 256 * sizeof(float), stream);
  stats_kernel<<<128, 256, 0, stream>>>(idx1, idx2, dotc, dotrc, gsum, gsq);
  finalize_kernel<<<1, 128, 0, stream>>>(gsum, gsq, gamma, beta, scalev, shiftv);
  output_kernel<<<392, 256, 0, stream>>>(idx1, idx2, dotc, dotrc, scalev, shiftv, out);
}

// Round 8
// 624.932 us; speedup vs baseline: 1.1342x; 1.1342x over previous
//
#include <hip/hip_runtime.h>
#include <stdint.h>

#define NP 25088   // B * oH * oW = 8*56*56
#define DD 576     // 64 * 3 * 3
#define KC 256     // centroids

// ---------------- unfold: x[8,64,56,56] -> P[n][d] (patch-major) -------------
// Patch-major layout so nearest_kernel's A-row reads are wave-uniform
// contiguous 64B chunks (-> s_load_dwordx16). Row stride 2304 B (64B-aligned).
__global__ __launch_bounds__(256) void unfold_kernel(const float* __restrict__ x,
                                                     float* __restrict__ P) {
  const int n0 = blockIdx.x * 16;                // 16 patches per block
#pragma unroll 1
  for (int rr = 0; rr < 36; ++rr) {              // 16*576/256
    const unsigned idx = rr * 256 + threadIdx.x; // 0..9215
    const int n = n0 + (int)(idx / 576u);
    const int d = (int)(idx % 576u);
    const int c = d / 9, r = d % 9;
    const int di = r / 3 - 1, dj = r % 3 - 1;
    const int b = n / 3136, hw = n % 3136;
    const int h = hw / 56 + di, w = hw % 56 + dj;
    float v = 0.0f;
    if (h >= 0 && h < 56 && w >= 0 && w < 56)
      v = x[(((size_t)b * 64 + c) * 56 + h) * 56 + w];
    P[(size_t)n * DD + d] = v;                   // consecutive tid -> consecutive d
  }
}

// ---------------- nearest: thread = centroid k, block = 16 patches -----------
// No LDS / no barriers in the main loop (R4-R7 evidence: the tiled scheme is
// LDS-pipe + barrier-lockstep bound at ~3x the VALU floor).
// Per 16-d chunk: B-row chunk per-lane (4x float4, contiguous per thread,
// L2-resident), A-patch chunk wave-uniform -> compiler emits s_load_dwordx16;
// inner loop is pure VALU: v_sub + v_add(|a|,|b|) tree = 2 instr/elem.
// Chunk sums are tree-reduced then added to per-m totals (36-term chains ->
// fp32 error ~1e-4, argmin-tie safe). Epilogue: 64-lane butterfly min + 512 B
// LDS cross-wave combine; k = tid, ascending -> strict < keeps lowest k (ties).
#define STEP(mm, ACC) do {                                          \
    const float* Ar_ = ap + (size_t)(mm) * DD;                      \
    const float4 a0 = *(const float4*)(Ar_);                        \
    const float4 a1 = *(const float4*)(Ar_ + 4);                    \
    const float4 a2 = *(const float4*)(Ar_ + 8);                    \
    const float4 a3 = *(const float4*)(Ar_ + 12);                   \
    const float s_ =                                                \
      ((((fabsf(a0.x - vb0.x) + fabsf(a0.y - vb0.y)) +              \
         (fabsf(a0.z - vb0.z) + fabsf(a0.w - vb0.w))) +             \
        ((fabsf(a1.x - vb1.x) + fabsf(a1.y - vb1.y)) +              \
         (fabsf(a1.z - vb1.z) + fabsf(a1.w - vb1.w)))) +            \
       (((fabsf(a2.x - vb2.x) + fabsf(a2.y - vb2.y)) +              \
         (fabsf(a2.z - vb2.z) + fabsf(a2.w - vb2.w))) +             \
        ((fabsf(a3.x - vb3.x) + fabsf(a3.y - vb3.y)) +              \
         (fabsf(a3.z - vb3.z) + fabsf(a3.w - vb3.w)))));            \
    ACC += s_;                                                      \
  } while (0)

#define REDUCE(mm, V) do {                                          \
    float bd_ = (V); int bk_ = tid;                                 \
    _Pragma("unroll")                                               \
    for (int off_ = 1; off_ < 64; off_ <<= 1) {                     \
      const float od_ = __shfl_xor(bd_, off_, 64);                  \
      const int ok_ = __shfl_xor(bk_, off_, 64);                    \
      if (od_ < bd_ || (od_ == bd_ && ok_ < bk_)) { bd_ = od_; bk_ = ok_; } \
    }                                                               \
    if (lane == 0) { sd[wv][mm] = bd_; si[wv][mm] = bk_; }          \
  } while (0)

__global__ __launch_bounds__(256, 4) void nearest_kernel(const float* __restrict__ A,
                                                         const float* __restrict__ C,
                                                         int* __restrict__ idx_out) {
  __shared__ float sd[4][16];
  __shared__ int si[4][16];

  const int tid = threadIdx.x;                 // = centroid k (0..255)
  const int lane = tid & 63, wv = tid >> 6;
  const int m0 = blockIdx.x * 16;              // 16 patches per block

  const float* ap = A + (size_t)m0 * DD;       // wave-uniform (blockIdx only)
  const float* bp = C + (size_t)tid * DD;      // per-lane centroid row

  // accumulators: named float4 components only (R3/R4: arrays => scratch)
  float4 acc0, acc1, acc2, acc3;
  acc0 = acc1 = acc2 = acc3 = make_float4(0.f, 0.f, 0.f, 0.f);

#pragma unroll 2
  for (int ch = 0; ch < 36; ++ch) {            // 36 * 16 = 576 d's
    const float4 vb0 = *(const float4*)(bp);
    const float4 vb1 = *(const float4*)(bp + 4);
    const float4 vb2 = *(const float4*)(bp + 8);
    const float4 vb3 = *(const float4*)(bp + 12);
    STEP(0,  acc0.x); STEP(1,  acc0.y); STEP(2,  acc0.z); STEP(3,  acc0.w);
    STEP(4,  acc1.x); STEP(5,  acc1.y); STEP(6,  acc1.z); STEP(7,  acc1.w);
    STEP(8,  acc2.x); STEP(9,  acc2.y); STEP(10, acc2.z); STEP(11, acc2.w);
    STEP(12, acc3.x); STEP(13, acc3.y); STEP(14, acc3.z); STEP(15, acc3.w);
    ap += 16; bp += 16;
  }

  REDUCE(0,  acc0.x); REDUCE(1,  acc0.y); REDUCE(2,  acc0.z); REDUCE(3,  acc0.w);
  REDUCE(4,  acc1.x); REDUCE(5,  acc1.y); REDUCE(6,  acc1.z); REDUCE(7,  acc1.w);
  REDUCE(8,  acc2.x); REDUCE(9,  acc2.y); REDUCE(10, acc2.z); REDUCE(11, acc2.w);
  REDUCE(12, acc3.x); REDUCE(13, acc3.y); REDUCE(14, acc3.z); REDUCE(15, acc3.w);

  __syncthreads();
  if (tid < 16) {
    float bd = sd[0][tid];
    int bk = si[0][tid];
#pragma unroll
    for (int w = 1; w < 4; ++w) {              // ascending wave => ascending k;
      const float od = sd[w][tid];             // strict < keeps lowest k on ties
      if (od < bd) { bd = od; bk = si[w][tid]; }
    }
    idx_out[m0 + tid] = bk;
  }
}

// ---------------- residual in place: P[n][d] -= C1[idx1[n]][d] ---------------
__global__ __launch_bounds__(256) void resid_kernel(float* __restrict__ P,
                                                    const float* __restrict__ C1,
                                                    const int* __restrict__ idx1) {
  const int n0 = blockIdx.x * 16;
#pragma unroll 1
  for (int rr = 0; rr < 9; ++rr) {             // 16*144 float4s / 256 threads
    const unsigned q = rr * 256 + threadIdx.x; // 0..2303
    const int n = n0 + (int)(q / 144u);
    const int dq = (int)(q % 144u);            // float4 index within row
    const int k = idx1[n];
    float4* pp = (float4*)(P + (size_t)n * DD + dq * 4);
    const float4 pv = *pp;
    const float4 cv = *(const float4*)(C1 + (size_t)k * DD + dq * 4);
    *pp = make_float4(pv.x - cv.x, pv.y - cv.y, pv.z - cv.z, pv.w - cv.w);
  }
}

// ---------------- BN stats: per-channel sum & sumsq of LUT outputs -----------
__global__ __launch_bounds__(256) void stats_kernel(const int* __restrict__ idx1,
                                                    const int* __restrict__ idx2,
                                                    const float* __restrict__ dotc,
                                                    const float* __restrict__ dotrc,
                                                    float* __restrict__ gsum,
                                                    float* __restrict__ gsq) {
  __shared__ float ssum[4][128], ssq[4][128];
  const int tid = threadIdx.x, lane = tid & 63, wv = tid >> 6;
  const int wid = blockIdx.x * 4 + wv;           // 0..511
  float s0 = 0.f, s1 = 0.f, q0 = 0.f, q1 = 0.f;
  for (int n = wid; n < NP; n += 512) {          // 25088 = 512*49
    const int k1 = idx1[n], k2 = idx2[n];
    const float2 u = ((const float2*)(dotc + (size_t)k1 * 128))[lane];
    const float2 v = ((const float2*)(dotrc + (size_t)k2 * 128))[lane];
    const float x0 = u.x + v.x, x1 = u.y + v.y;
    s0 += x0; s1 += x1; q0 += x0 * x0; q1 += x1 * x1;
  }
  ssum[wv][lane * 2] = s0; ssum[wv][lane * 2 + 1] = s1;
  ssq[wv][lane * 2] = q0;  ssq[wv][lane * 2 + 1] = q1;
  __syncthreads();
  if (tid < 128) {
    const float s = ssum[0][tid] + ssum[1][tid] + ssum[2][tid] + ssum[3][tid];
    const float q = ssq[0][tid] + ssq[1][tid] + ssq[2][tid] + ssq[3][tid];
    atomicAdd(&gsum[tid], s);
    atomicAdd(&gsq[tid], q);
  }
}

__global__ void finalize_kernel(const float* __restrict__ gsum,
                                const float* __restrict__ gsq,
                                const float* __restrict__ gamma,
                                const float* __restrict__ beta,
                                float* __restrict__ scalev,
                                float* __restrict__ shiftv) {
  const int c = threadIdx.x;                     // 128
  const float mean = gsum[c] * (1.0f / NP);
  const float var = gsq[c] * (1.0f / NP) - mean * mean;
  const float inv = rsqrtf(var + 1e-5f);
  const float sc = gamma[c] * inv;
  scalev[c] = sc;
  shiftv[c] = beta[c] - mean * sc;
}

// ---------------- output: LUT gather + affine BN + [B,C,H,W] store -----------
__global__ __launch_bounds__(256) void output_kernel(const int* __restrict__ idx1,
                                                     const int* __restrict__ idx2,
                                                     const float* __restrict__ dotc,
                                                     const float* __restrict__ dotrc,
                                                     const float* __restrict__ scalev,
                                                     const float* __restrict__ shiftv,
                                                     float* __restrict__ out) {
  __shared__ float vals[64][128];                // [n-local][c]  32 KB
  const int tid = threadIdx.x, lane = tid & 63, wv = tid >> 6;
  const int blk = blockIdx.x;                    // 392 = 8 * 49
  const int b = blk / 49, hw0 = (blk % 49) * 64;
  const int n0 = b * 3136 + hw0;
  const float sc0 = scalev[lane * 2], sc1 = scalev[lane * 2 + 1];
  const float sh0 = shiftv[lane * 2], sh1 = shiftv[lane * 2 + 1];
  for (int t = 0; t < 16; ++t) {
    const int nn = wv * 16 + t;
    const int n = n0 + nn;
    const int k1 = idx1[n], k2 = idx2[n];
    const float2 u = ((const float2*)(dotc + (size_t)k1 * 128))[lane];
    const float2 v = ((const float2*)(dotrc + (size_t)k2 * 128))[lane];
    *(float2*)&vals[nn][lane * 2] =
        make_float2(sc0 * (u.x + v.x) + sh0, sc1 * (u.y + v.y) + sh1);
  }
  __syncthreads();
  const int c = tid >> 1, half = tid & 1;
  float* op = out + ((size_t)b * 128 + c) * 3136 + hw0 + half * 32;
#pragma unroll
  for (int i = 0; i < 32; i += 4) {
    float4 w4;
    w4.x = vals[half * 32 + i + 0][c];
    w4.y = vals[half * 32 + i + 1][c];
    w4.z = vals[half * 32 + i + 2][c];
    w4.w = vals[half * 32 + i + 3][c];
    *(float4*)(op + i) = w4;
  }
}

extern "C" void kernel_launch(void* const* d_in, const int* in_sizes, int n_in,
                              void* d_out, int out_size, void* d_ws, size_t ws_size,
                              hipStream_t stream) {
  const float* x     = (const float*)d_in[0];
  const float* cent  = (const float*)d_in[1];
  const float* rcent = (const float*)d_in[2];
  const float* dotc  = (const float*)d_in[3];
  const float* dotrc = (const float*)d_in[4];
  const float* gamma = (const float*)d_in[5];
  const float* beta  = (const float*)d_in[6];
  float* out = (float*)d_out;

  // workspace layout (~58 MB)
  float* P   = (float*)d_ws;                 // [25088][576] patch-major
  int* idx1  = (int*)(P + (size_t)NP * DD);
  int* idx2  = idx1 + NP;
  float* gsum   = (float*)(idx2 + NP);       // [128]
  float* gsq    = gsum + 128;                // [128]
  float* scalev = gsq + 128;                 // [128]
  float* shiftv = scalev + 128;              // [128]

  unfold_kernel<<<1568, 256, 0, stream>>>(x, P);
  nearest_kernel<<<1568, 256, 0, stream>>>(P, cent, idx1);
  resid_kernel<<<1568, 256, 0, stream>>>(P, cent, idx1);
  nearest_kernel<<<1568, 256, 0, stream>>>(P, rcent, idx2);
  hipMemsetAsync(gsum, 0, 256 * sizeof(float), stream);
  stats_kernel<<<128, 256, 0, stream>>>(idx1, idx2, dotc, dotrc, gsum, gsq);
  finalize_kernel<<<1, 128, 0, stream>>>(gsum, gsq, gamma, beta, scalev, shiftv);
  output_kernel<<<392, 256, 0, stream>>>(idx1, idx2, dotc, dotrc, scalev, shiftv, out);
}